// Round 14
// baseline (148.625 us; speedup 1.0000x reference)
//
#include <hip/hip_runtime.h>
#include <math.h>

typedef unsigned int u32;
typedef unsigned short u16;
typedef __attribute__((ext_vector_type(8))) short short8v;   // 8 bf16 = 4 VGPR
typedef __attribute__((ext_vector_type(4))) float f32x4;

#define NDF 11
#define MAXN 35
#define RS 72          // padded row stride in bf16 elems (144 B; 16B-aligned rows)

__device__ __forceinline__ u16 f2bf(float x) {
    u32 b = __float_as_uint(x);
    u32 r = (b + 0x7fffu + ((b >> 16) & 1u)) >> 16;
    return (u16)r;
}
__device__ __forceinline__ float bf2f(u16 h) {
    return __uint_as_float(((u32)h) << 16);
}
__device__ __forceinline__ void splitbf(float x, u16& hi, u16& lo) {
    hi = f2bf(x);
    lo = f2bf(x - bf2f(hi));
}

// ---------------------------------------------------------------------------
// k_prep: split-bf16 (hi|lo planes) transposed weight images + BN constants.
// ---------------------------------------------------------------------------
__global__ void k_prep(const float* __restrict__ lin_w,
                       const float* __restrict__ nn1_w, const float* __restrict__ nn2_w,
                       const float* __restrict__ nd1_w, const float* __restrict__ nd2_w,
                       const float* __restrict__ pd1_w, const float* __restrict__ pd2_w,
                       const float* __restrict__ nd_g, const float* __restrict__ nd_be,
                       const float* __restrict__ nd_rm, const float* __restrict__ nd_rv,
                       const float* __restrict__ pd_g, const float* __restrict__ pd_be,
                       const float* __restrict__ pd_rm, const float* __restrict__ pd_rv,
                       u16* __restrict__ lint, u16* __restrict__ w1t3,
                       u16* __restrict__ w2t3, float* __restrict__ bnc)
{
    const int t0 = blockIdx.x * 256 + threadIdx.x;     // 16 blocks -> 4096
    if (t0 < 64) {
        const float sc = nd_g[t0] / sqrtf(nd_rv[t0] + 1e-5f);
        bnc[t0]       = sc;
        bnc[64 + t0]  = nd_be[t0] - nd_rm[t0] * sc;
        const float sp = pd_g[t0] / sqrtf(pd_rv[t0] + 1e-5f);
        bnc[128 + t0] = sp;
        bnc[192 + t0] = pd_be[t0] - pd_rm[t0] * sp;
    }
    for (int i = t0; i < 64*RS; i += 4096) {
        const int n = i / RS, k = i % RS;
        const float v = (k < 33) ? lin_w[k*64 + n] : 0.f;
        u16 h, l; splitbf(v, h, l);
        lint[i] = h; lint[64*RS + i] = l;
    }
    for (int b = 0; b < 3; b++) {
        const float* M = (b == 0) ? nn1_w : (b == 1) ? nd1_w : pd1_w;
        u16* dst = w1t3 + (size_t)b * 2 * 64 * RS;
        for (int i = t0; i < 64*RS; i += 4096) {
            const int o = i / RS, k = i % RS;
            const float v = (k < 64) ? M[k*64 + o] : 0.f;
            u16 h, l; splitbf(v, h, l);
            dst[i] = h; dst[64*RS + i] = l;
        }
        u16* d2 = w2t3 + (size_t)b * 2 * 16 * RS;
        for (int i = t0; i < 16*RS; i += 4096) {
            const int n = i / RS, k = i % RS;
            float v = 0.f;
            if (k < 64) {
                if (b == 0)      { if (n == 14)           v = nn2_w[k]; }
                else if (b == 1) { if (n < 11)            v = nd2_w[k*11 + n]; }
                else             { if (n >= 11 && n < 14) v = pd2_w[k*3 + (n-11)]; }
            }
            u16 h, l; splitbf(v, h, l);
            d2[i] = h; d2[16*RS + i] = l;
        }
    }
}

// ---------------------------------------------------------------------------
// k_mfma: wave-independent (no barriers/atomics). 2 chunks x 16 graphs/wave,
// X-buffer reused as T. Split-bf16 for phase A + nn branch; decode single.
// Boundary flags: exact rule (saturated args exempt) packed to one u32/wave
// via __ballot. C/D layout (m89): col=lane&15, row=(lane>>4)*4+reg.
// ---------------------------------------------------------------------------
__global__ __launch_bounds__(256)
void k_mfma(const float* __restrict__ z, const float* __restrict__ tpr,
            const float* __restrict__ lin_b,
            const u16* __restrict__ lint, const u16* __restrict__ w1t3,
            const u16* __restrict__ w2t3,
            const float* __restrict__ nn1_b, const float* __restrict__ nd1_b,
            const float* __restrict__ pd1_b,
            const float* __restrict__ nn2_b, const float* __restrict__ nd2_b,
            const float* __restrict__ pd2_b,
            const float* __restrict__ bnc,
            const float* __restrict__ nsc, const float* __restrict__ nsh,
            const float* __restrict__ psc, const float* __restrict__ psh,
            float* __restrict__ nf_g, float* __restrict__ pos_g,
            int* __restrict__ nn_int, float* __restrict__ out_nn,
            u32* __restrict__ fmask, int B)
{
    __shared__ __align__(16) u16 sXT[4][2*16*RS];  // X, then T (hi | lo planes)
    __shared__ __align__(16) u16 sH[4][2*16*RS];   // H (hi | lo planes)

    const int t    = threadIdx.x;
    const int lane = t & 63;
    const int w    = t >> 6;
    u16* mX = sXT[w];        // alias: X during stage+phaseA, T afterwards
    u16* mH = sH[w];

    const int W = blockIdx.x * 4 + w;            // global wave id

    auto zeroXpad = [&]() {
        if (lane < 16) {
            #pragma unroll
            for (int pl = 0; pl < 2; pl++) {
                u16* base = mX + pl*16*RS;
                base[lane*RS + 33] = 0;
                u32* p = (u32*)(base + lane*RS + 34);
                #pragma unroll
                for (int q = 0; q < 15; q++) p[q] = 0;
            }
        }
    };

    auto gfrag = [&](const u16* base, int row0, int ks) -> short8v {
        const uint4 v = *(const uint4*)(base + (row0 + (lane & 15))*RS + ks*32 + ((lane >> 4) * 8));
        return __builtin_bit_cast(short8v, v);
    };
    short8v fLin[4][2], fW[3][4][2], fH2[3][2];
    #pragma unroll
    for (int nt = 0; nt < 4; nt++)
        #pragma unroll
        for (int ks = 0; ks < 2; ks++)
            fLin[nt][ks] = gfrag(lint, nt*16, ks);
    #pragma unroll
    for (int b = 0; b < 3; b++)
        #pragma unroll
        for (int nt = 0; nt < 4; nt++)
            #pragma unroll
            for (int ks = 0; ks < 2; ks++)
                fW[b][nt][ks] = gfrag(w1t3 + (size_t)b*2*64*RS, nt*16, ks);
    #pragma unroll
    for (int b = 0; b < 3; b++)
        #pragma unroll
        for (int ks = 0; ks < 2; ks++)
            fH2[b][ks] = gfrag(w2t3 + (size_t)b*2*16*RS, 0, ks);

    const int col = lane & 15;
    float bLin[4], bB1[3][4], bSc[2][4], bBi[2][4];
    #pragma unroll
    for (int nt = 0; nt < 4; nt++) {
        const int c = nt*16 + col;
        bLin[nt]    = lin_b[c];
        bB1[0][nt]  = nn1_b[c];
        bB1[1][nt]  = nd1_b[c];
        bB1[2][nt]  = pd1_b[c];
        bSc[0][nt]  = bnc[c];        bBi[0][nt] = bnc[64 + c];
        bSc[1][nt]  = bnc[128 + c];  bBi[1][nt] = bnc[192 + c];
    }
    const float epb = (col < 11) ? nd2_b[col] : (col < 14) ? pd2_b[col - 11] : 0.f;
    const float nn2b = nn2_b[0];
    const float a_ns = nsc[0], a_nh = nsh[0], a_ps = psc[0], a_ph = psh[0];

    auto ldfrag = [&](const u16* base, int ks) -> short8v {
        const uint4 v = *(const uint4*)(base + (lane & 15)*RS + ks*32 + ((lane >> 4) * 8));
        return __builtin_bit_cast(short8v, v);
    };

    u32 wavebits = 0;

    #pragma unroll 1
    for (int c = 0; c < 2; c++) {
        const int gb = (W*2 + c) * 16;
        if (gb >= B) break;

        zeroXpad();

        // ---- stage X (hi|lo planes) ----
        {
            const float4* zb = (const float4*)(z + (size_t)gb * 32);
            const float4 v0 = zb[(lane >> 2)*8 + (lane & 3)*2];
            const float4 v1 = zb[(lane >> 2)*8 + (lane & 3)*2 + 1];
            const float xv[8] = {v0.x, v0.y, v0.z, v0.w, v1.x, v1.y, v1.z, v1.w};
            u32 pkh[4], pkl[4];
            #pragma unroll
            for (int q = 0; q < 4; q++) {
                u16 h0, l0, h1, l1;
                splitbf(xv[2*q], h0, l0);
                splitbf(xv[2*q+1], h1, l1);
                pkh[q] = (u32)h0 | ((u32)h1 << 16);
                pkl[q] = (u32)l0 | ((u32)l1 << 16);
            }
            *(uint4*)(mX + (lane >> 2)*RS + (lane & 3)*8) = *(uint4*)pkh;
            *(uint4*)(mX + 16*RS + (lane >> 2)*RS + (lane & 3)*8) = *(uint4*)pkl;
            if (lane < 16) {
                u16 h, l; splitbf(tpr[gb + lane], h, l);
                mX[lane*RS + 32] = h;
                mX[16*RS + lane*RS + 32] = l;
            }
        }

        // ---- phase A (split, 6 MFMA/nt): H = X @ lin + lin_b ----
        const short8v a0h = ldfrag(mX, 0);
        const short8v a1h = ldfrag(mX, 1);
        const short8v a0l = ldfrag(mX + 16*RS, 0);
        const short8v a1l = ldfrag(mX + 16*RS, 1);
        #pragma unroll
        for (int nt = 0; nt < 4; nt++) {
            const short8v bl0 = gfrag(lint + 64*RS, nt*16, 0);
            const short8v bl1 = gfrag(lint + 64*RS, nt*16, 1);
            f32x4 acc = {0.f, 0.f, 0.f, 0.f};
            acc = __builtin_amdgcn_mfma_f32_16x16x32_bf16(a0h, fLin[nt][0], acc, 0, 0, 0);
            acc = __builtin_amdgcn_mfma_f32_16x16x32_bf16(a1h, fLin[nt][1], acc, 0, 0, 0);
            acc = __builtin_amdgcn_mfma_f32_16x16x32_bf16(a0h, bl0, acc, 0, 0, 0);
            acc = __builtin_amdgcn_mfma_f32_16x16x32_bf16(a1h, bl1, acc, 0, 0, 0);
            acc = __builtin_amdgcn_mfma_f32_16x16x32_bf16(a0l, fLin[nt][0], acc, 0, 0, 0);
            acc = __builtin_amdgcn_mfma_f32_16x16x32_bf16(a1l, fLin[nt][1], acc, 0, 0, 0);
            const float bias = bLin[nt];
            #pragma unroll
            for (int r = 0; r < 4; r++) {
                const int row = (lane >> 4)*4 + r;
                u16 hh, hl; splitbf(acc[r] + bias, hh, hl);
                mH[row*RS + nt*16 + col] = hh;
                mH[16*RS + row*RS + nt*16 + col] = hl;
            }
        }

        u16* mT = mX;   // X dead; reuse as T
        const short8v h0h = ldfrag(mH, 0);
        const short8v h1h = ldfrag(mH, 1);
        f32x4 acc2 = {0.f, 0.f, 0.f, 0.f};

        // ---- nn branch (b=0, split) ----
        {
            const short8v h0l = ldfrag(mH + 16*RS, 0);
            const short8v h1l = ldfrag(mH + 16*RS, 1);
            const u16* wlo = w1t3 + 64*RS;   // b=0 lo plane
            #pragma unroll
            for (int nt = 0; nt < 4; nt++) {
                const short8v wl0 = gfrag(wlo, nt*16, 0);
                const short8v wl1 = gfrag(wlo, nt*16, 1);
                f32x4 acc = {0.f, 0.f, 0.f, 0.f};
                acc = __builtin_amdgcn_mfma_f32_16x16x32_bf16(h0h, fW[0][nt][0], acc, 0, 0, 0);
                acc = __builtin_amdgcn_mfma_f32_16x16x32_bf16(h1h, fW[0][nt][1], acc, 0, 0, 0);
                acc = __builtin_amdgcn_mfma_f32_16x16x32_bf16(h0h, wl0, acc, 0, 0, 0);
                acc = __builtin_amdgcn_mfma_f32_16x16x32_bf16(h1h, wl1, acc, 0, 0, 0);
                acc = __builtin_amdgcn_mfma_f32_16x16x32_bf16(h0l, fW[0][nt][0], acc, 0, 0, 0);
                acc = __builtin_amdgcn_mfma_f32_16x16x32_bf16(h1l, fW[0][nt][1], acc, 0, 0, 0);
                const float bb = bB1[0][nt];
                #pragma unroll
                for (int r = 0; r < 4; r++) {
                    const int row = (lane >> 4)*4 + r;
                    float rv = acc[r] + bb;
                    rv = rv > 0.f ? rv : 0.f;
                    u16 th, tl; splitbf(rv, th, tl);
                    mT[row*RS + nt*16 + col] = th;
                    mT[16*RS + row*RS + nt*16 + col] = tl;
                }
            }
            const short8v t0h = ldfrag(mT, 0);
            const short8v t1h = ldfrag(mT, 1);
            const short8v t0l = ldfrag(mT + 16*RS, 0);
            const short8v t1l = ldfrag(mT + 16*RS, 1);
            const short8v g2l0 = gfrag(w2t3 + 16*RS, 0, 0);
            const short8v g2l1 = gfrag(w2t3 + 16*RS, 0, 1);
            acc2 = __builtin_amdgcn_mfma_f32_16x16x32_bf16(t0h, fH2[0][0], acc2, 0, 0, 0);
            acc2 = __builtin_amdgcn_mfma_f32_16x16x32_bf16(t1h, fH2[0][1], acc2, 0, 0, 0);
            acc2 = __builtin_amdgcn_mfma_f32_16x16x32_bf16(t0h, g2l0, acc2, 0, 0, 0);
            acc2 = __builtin_amdgcn_mfma_f32_16x16x32_bf16(t1h, g2l1, acc2, 0, 0, 0);
            acc2 = __builtin_amdgcn_mfma_f32_16x16x32_bf16(t0l, fH2[0][0], acc2, 0, 0, 0);
            acc2 = __builtin_amdgcn_mfma_f32_16x16x32_bf16(t1l, fH2[0][1], acc2, 0, 0, 0);
        }

        // ---- decode branches (b=1,2, single-bf16) ----
        #pragma unroll
        for (int b = 1; b < 3; b++) {
            #pragma unroll
            for (int nt = 0; nt < 4; nt++) {
                f32x4 acc = {0.f, 0.f, 0.f, 0.f};
                acc = __builtin_amdgcn_mfma_f32_16x16x32_bf16(h0h, fW[b][nt][0], acc, 0, 0, 0);
                acc = __builtin_amdgcn_mfma_f32_16x16x32_bf16(h1h, fW[b][nt][1], acc, 0, 0, 0);
                const float bb = bB1[b][nt];
                const float sc = bSc[b-1][nt];
                const float bi = bBi[b-1][nt];
                #pragma unroll
                for (int r = 0; r < 4; r++) {
                    const int row = (lane >> 4)*4 + r;
                    float rv = acc[r] + bb;
                    rv = rv > 0.f ? rv : 0.f;
                    mT[row*RS + nt*16 + col] = f2bf(fmaf(rv, sc, bi));
                }
            }
            const short8v t0 = ldfrag(mT, 0);
            const short8v t1 = ldfrag(mT, 1);
            acc2 = __builtin_amdgcn_mfma_f32_16x16x32_bf16(t0, fH2[b][0], acc2, 0, 0, 0);
            acc2 = __builtin_amdgcn_mfma_f32_16x16x32_bf16(t1, fH2[b][1], acc2, 0, 0, 0);
        }

        // ---- epilogue: cols 0-10 nf, 11-13 pos, 14 logit ----
        u32 chunkbits = 0;
        #pragma unroll
        for (int r = 0; r < 4; r++) {
            const int g = gb + (lane >> 4)*4 + r;
            const float v = acc2[r];
            bool fl = false;
            if (col < 11) {
                nf_g[(size_t)g*NDF + col] = fmaf(v + epb, a_ns, a_nh);
            } else if (col < 14) {
                pos_g[(size_t)g*3 + (col - 11)] = fmaf(v + epb, a_ps, a_ph);
            } else if (col == 14) {
                const float logit = v + nn2b;
                const float arg = fmaf(1.f / (1.f + expf(-logit)), 30.f, 5.f);
                int n;
                if (arg < 5.03f) {
                    n = 5;                       // arg > 5 in BOTH precisions -> floor 5
                } else if (arg >= 34.97f) {
                    // 34 vs 35 decided by f64-sigmoid saturation (cutoff ~37.4)
                    if (logit >= 38.f)      n = 35;
                    else { n = 34; fl = (logit > 37.f); }   // narrow band -> f64
                } else {
                    n = (int)arg;
                    fl = fabsf(arg - rintf(arg)) < 0.03f;
                }
                nn_int[g] = n;
                out_nn[g] = (float)n;
            }
            const unsigned long long m = __ballot(fl);
            chunkbits |= (u32)(((m >> 14) & 1ull) << r)
                       | (u32)(((m >> 30) & 1ull) << (4 + r))
                       | (u32)(((m >> 46) & 1ull) << (8 + r))
                       | (u32)(((m >> 62) & 1ull) << (12 + r));
        }
        wavebits |= chunkbits << (16 * c);
    }

    if (lane == 0) fmask[W] = wavebits;
    (void)B;
}

// ---------------------------------------------------------------------------
// k_fix: exact f64 re-derivation for flagged graphs. One u32 bitmask per
// wave (32 graphs) -> single scalar load; iterate set bits.
// ---------------------------------------------------------------------------
__global__ __launch_bounds__(256)
void k_fix(const float* __restrict__ z, const float* __restrict__ tpr,
           const float* __restrict__ lin_w, const float* __restrict__ lin_b,
           const float* __restrict__ nn1_w, const float* __restrict__ nn1_b,
           const float* __restrict__ nn2_w, const float* __restrict__ nn2_b,
           const u32* __restrict__ fmask, int* __restrict__ nn_int,
           float* __restrict__ out_nn, int B)
{
    __shared__ __align__(16) double hb[4][64];
    const int lane = threadIdx.x & 63;
    const int w = threadIdx.x >> 6;
    const int W = (blockIdx.x * 256 + threadIdx.x) >> 6;   // 4096 waves
    u32 mask = fmask[W];
    const double b2 = (double)nn2_b[0];

    while (mask) {
        const int bpos = __ffs(mask) - 1;
        mask &= mask - 1;
        const int g = W * 32 + bpos;

        double h0 = (double)lin_b[lane], h1 = 0.0, h2 = 0.0, h3 = 0.0;
        for (int j = 0; j < 32; j += 4) {
            h0 = fma((double)z[(size_t)g*32 + j],     (double)lin_w[j*64 + lane],     h0);
            h1 = fma((double)z[(size_t)g*32 + j + 1], (double)lin_w[(j+1)*64 + lane], h1);
            h2 = fma((double)z[(size_t)g*32 + j + 2], (double)lin_w[(j+2)*64 + lane], h2);
            h3 = fma((double)z[(size_t)g*32 + j + 3], (double)lin_w[(j+3)*64 + lane], h3);
        }
        h0 = fma((double)tpr[g], (double)lin_w[32*64 + lane], h0);
        hb[w][lane] = (h0 + h1) + (h2 + h3);

        const double2* hp = (const double2*)hb[w];
        double a0 = (double)nn1_b[lane], a1 = 0.0, a2 = 0.0, a3 = 0.0;
        for (int m = 0; m < 16; m++) {
            const double2 p = hp[2*m];
            const double2 q = hp[2*m + 1];
            a0 = fma(p.x, (double)nn1_w[(4*m+0)*64 + lane], a0);
            a1 = fma(p.y, (double)nn1_w[(4*m+1)*64 + lane], a1);
            a2 = fma(q.x, (double)nn1_w[(4*m+2)*64 + lane], a2);
            a3 = fma(q.y, (double)nn1_w[(4*m+3)*64 + lane], a3);
        }
        const double a = (a0 + a1) + (a2 + a3);
        double v = (a > 0.0) ? a * (double)nn2_w[lane] : 0.0;
        for (int d = 32; d > 0; d >>= 1) v += __shfl_xor(v, d);
        const double logit = v + b2;

        if (lane == 0) {
            const double sg = 1.0 / (1.0 + exp(-logit));
            const int n = (int)(sg * 30.0 + 5.0);
            nn_int[g] = n;
            out_nn[g] = (float)n;
        }
    }
    (void)B;
}

// ---------------------------------------------------------------------------
// Prefix sums via wave shuffle scans (1 barrier each).
// ---------------------------------------------------------------------------
__global__ __launch_bounds__(256)
void k_scan1(const int* __restrict__ a, int* __restrict__ part, int* __restrict__ bsum)
{
    const int t = threadIdx.x;
    const int lane = t & 63;
    const int wid = t >> 6;
    const int g = blockIdx.x * 256 + t;
    int v = a[g];
    #pragma unroll
    for (int d = 1; d < 64; d <<= 1) {
        const int u = __shfl_up(v, d);
        if (lane >= d) v += u;
    }
    __shared__ int ws[4];
    if (lane == 63) ws[wid] = v;
    __syncthreads();
    int add = 0;
    #pragma unroll
    for (int q = 0; q < 3; q++) if (q < wid) add += ws[q];
    v += add;
    part[g] = v;
    if (t == 255) bsum[blockIdx.x] = v;
}

__global__ void k_scan2(const int* __restrict__ bsum, int* __restrict__ boff, int nb)
{
    const int t = threadIdx.x;     // nb threads (512)
    const int lane = t & 63;
    const int wid = t >> 6;        // 8 waves
    const int orig = bsum[t];
    int v = orig;
    #pragma unroll
    for (int d = 1; d < 64; d <<= 1) {
        const int u = __shfl_up(v, d);
        if (lane >= d) v += u;
    }
    __shared__ int ws[8];
    if (lane == 63) ws[wid] = v;
    __syncthreads();
    int add = 0;
    #pragma unroll
    for (int q = 0; q < 7; q++) if (q < wid) add += ws[q];
    v += add;
    boff[t] = v - orig;            // exclusive
    if (t == nb - 1) boff[nb] = v; // grand total sentinel
}

// ---------------------------------------------------------------------------
// k_expand: 2 rows/thread; boff staged in LDS (level-1 search hits LDS),
// level-2 over part[] in L2; LDS repack; coalesced float4 stores.
// Rows >= total repeat graph B-1 (JAX total_repeat_length padding).
// ---------------------------------------------------------------------------
__global__ __launch_bounds__(256)
void k_expand(const int* __restrict__ part, const int* __restrict__ boff,
              const float* __restrict__ nf_g, const float* __restrict__ pos_g,
              float* __restrict__ out, int B, int T, int nb)
{
    __shared__ __align__(16) float s_nf[512*NDF];
    __shared__ __align__(16) float s_ps[512*3];
    __shared__ int s_boff[513];
    const int t = threadIdx.x;
    for (int i = t; i <= nb; i += 256) s_boff[i] = boff[i];
    __syncthreads();

    const int r0 = blockIdx.x * 512 + 2*t;

    int blo = 0, bhi = nb - 1;
    while (blo < bhi) {
        const int m = (blo + bhi + 1) >> 1;
        if (s_boff[m] <= r0) blo = m; else bhi = m - 1;
    }
    const int bi = blo;
    const int lr = r0 - s_boff[bi];
    int lo = 0, hi2 = 256;
    while (lo < hi2) {
        const int m = (lo + hi2) >> 1;
        if (part[bi*256 + m] <= lr) lo = m + 1; else hi2 = m;
    }
    int i0 = bi*256 + lo;
    i0 = (i0 < B) ? i0 : B - 1;
    const int Ci0 = s_boff[i0 >> 8] + part[i0];
    const int i1 = ((r0 + 1) >= Ci0 && i0 < B - 1) ? i0 + 1 : i0;

    #pragma unroll
    for (int j = 0; j < NDF; j++) {
        s_nf[(2*t)*NDF + j]     = nf_g[(size_t)i0*NDF + j];
        s_nf[(2*t + 1)*NDF + j] = nf_g[(size_t)i1*NDF + j];
    }
    #pragma unroll
    for (int j = 0; j < 3; j++) {
        s_ps[(2*t)*3 + j]     = pos_g[(size_t)i0*3 + j];
        s_ps[(2*t + 1)*3 + j] = pos_g[(size_t)i1*3 + j];
    }
    __syncthreads();

    float4* onf = (float4*)(out + (size_t)blockIdx.x * 512 * NDF);
    const float4* snf = (const float4*)s_nf;
    #pragma unroll
    for (int q = 0; q < 6; q++) {
        const int idx = q*256 + t;
        if (idx < 512*NDF/4) onf[idx] = snf[idx];
    }
    float4* ops = (float4*)(out + (size_t)T*NDF + (size_t)blockIdx.x * 512 * 3);
    const float4* sps = (const float4*)s_ps;
    #pragma unroll
    for (int q = 0; q < 2; q++) {
        const int idx = q*256 + t;
        if (idx < 384) ops[idx] = sps[idx];
    }
}

// ---------------------------------------------------------------------------
extern "C" void kernel_launch(void* const* d_in, const int* in_sizes, int n_in,
                              void* d_out, int out_size, void* d_ws, size_t ws_size,
                              hipStream_t stream)
{
    const float* z     = (const float*)d_in[0];
    const float* tpr   = (const float*)d_in[1];
    const int    B     = in_sizes[1];
    const int    T     = B * MAXN;

    const float* lin_w = (const float*)d_in[3];
    const float* lin_b = (const float*)d_in[4];
    const float* nn1_w = (const float*)d_in[5];
    const float* nn1_b = (const float*)d_in[6];
    const float* nn2_w = (const float*)d_in[7];
    const float* nn2_b = (const float*)d_in[8];
    const float* nd1_w = (const float*)d_in[9];
    const float* nd1_b = (const float*)d_in[10];
    const float* nd_g  = (const float*)d_in[11];
    const float* nd_be = (const float*)d_in[12];
    const float* nd_rm = (const float*)d_in[13];
    const float* nd_rv = (const float*)d_in[14];
    const float* nd2_w = (const float*)d_in[15];
    const float* nd2_b = (const float*)d_in[16];
    const float* pd1_w = (const float*)d_in[17];
    const float* pd1_b = (const float*)d_in[18];
    const float* pd_g  = (const float*)d_in[19];
    const float* pd_be = (const float*)d_in[20];
    const float* pd_rm = (const float*)d_in[21];
    const float* pd_rv = (const float*)d_in[22];
    const float* pd2_w = (const float*)d_in[23];
    const float* pd2_b = (const float*)d_in[24];
    const float* nsc   = (const float*)d_in[25];
    const float* nsh   = (const float*)d_in[26];
    const float* psc   = (const float*)d_in[27];
    const float* psh   = (const float*)d_in[28];

    float* out = (float*)d_out;

    char* wsp = (char*)d_ws;
    size_t off = 0;
    auto take = [&](size_t bytes) { void* p = wsp + off; off = (off + bytes + 255) & ~(size_t)255; return p; };

    u16*   lint  = (u16*)take(2*64*RS*sizeof(u16));
    u16*   w1t3  = (u16*)take(3*2*64*RS*sizeof(u16));
    u16*   w2t3  = (u16*)take(3*2*16*RS*sizeof(u16));
    float* bnc   = (float*)take(256*sizeof(float));
    u32*   fmask = (u32*)take((size_t)(B/32)*sizeof(u32));
    float* nf_g  = (float*)take((size_t)B*NDF*sizeof(float));
    float* pos_g = (float*)take((size_t)B*3*sizeof(float));
    int*   nn_i  = (int*)take((size_t)B*sizeof(int));
    int*   part  = (int*)take((size_t)B*sizeof(int));
    int*   bsum  = (int*)take(4096*sizeof(int));
    int*   boff  = (int*)take(4096*sizeof(int));

    const int nb = B / 256;   // 512

    k_prep<<<16, 256, 0, stream>>>(lin_w, nn1_w, nn2_w, nd1_w, nd2_w, pd1_w, pd2_w,
                                   nd_g, nd_be, nd_rm, nd_rv,
                                   pd_g, pd_be, pd_rm, pd_rv,
                                   lint, w1t3, w2t3, bnc);

    k_mfma<<<B/128, 256, 0, stream>>>(z, tpr, lin_b, lint, w1t3, w2t3,
                                      nn1_b, nd1_b, pd1_b, nn2_b, nd2_b, pd2_b,
                                      bnc, nsc, nsh, psc, psh,
                                      nf_g, pos_g, nn_i, out + (size_t)T*14,
                                      fmask, B);

    k_fix<<<1024, 256, 0, stream>>>(z, tpr, lin_w, lin_b, nn1_w, nn1_b, nn2_w, nn2_b,
                                    fmask, nn_i, out + (size_t)T*14, B);

    k_scan1<<<nb, 256, 0, stream>>>(nn_i, part, bsum);
    k_scan2<<<1, nb, 0, stream>>>(bsum, boff, nb);

    k_expand<<<T/512, 256, 0, stream>>>(part, boff, nf_g, pos_g, out, B, T, nb);

    (void)n_in; (void)out_size; (void)ws_size;
}

// Round 15
// 136.125 us; speedup vs baseline: 1.0918x; 1.0918x over previous
//
#include <hip/hip_runtime.h>
#include <math.h>

typedef unsigned int u32;
typedef unsigned short u16;
typedef unsigned long long u64;
typedef __attribute__((ext_vector_type(8))) short short8v;   // 8 bf16 = 4 VGPR
typedef __attribute__((ext_vector_type(4))) float f32x4;

#define NDF 11
#define MAXN 35
#define RS 72          // padded row stride in bf16 elems (144 B; 16B-aligned rows)

__device__ __forceinline__ u16 f2bf(float x) {
    u32 b = __float_as_uint(x);
    u32 r = (b + 0x7fffu + ((b >> 16) & 1u)) >> 16;
    return (u16)r;
}
__device__ __forceinline__ float bf2f(u16 h) {
    return __uint_as_float(((u32)h) << 16);
}
__device__ __forceinline__ void splitbf(float x, u16& hi, u16& lo) {
    hi = f2bf(x);
    lo = f2bf(x - bf2f(hi));
}

// ---------------------------------------------------------------------------
// k_prep: split-bf16 (hi|lo planes) transposed weight images + BN constants.
// ---------------------------------------------------------------------------
__global__ void k_prep(const float* __restrict__ lin_w,
                       const float* __restrict__ nn1_w, const float* __restrict__ nn2_w,
                       const float* __restrict__ nd1_w, const float* __restrict__ nd2_w,
                       const float* __restrict__ pd1_w, const float* __restrict__ pd2_w,
                       const float* __restrict__ nd_g, const float* __restrict__ nd_be,
                       const float* __restrict__ nd_rm, const float* __restrict__ nd_rv,
                       const float* __restrict__ pd_g, const float* __restrict__ pd_be,
                       const float* __restrict__ pd_rm, const float* __restrict__ pd_rv,
                       u16* __restrict__ lint, u16* __restrict__ w1t3,
                       u16* __restrict__ w2t3, float* __restrict__ bnc)
{
    const int t0 = blockIdx.x * 256 + threadIdx.x;     // 16 blocks -> 4096
    if (t0 < 64) {
        const float sc = nd_g[t0] / sqrtf(nd_rv[t0] + 1e-5f);
        bnc[t0]       = sc;
        bnc[64 + t0]  = nd_be[t0] - nd_rm[t0] * sc;
        const float sp = pd_g[t0] / sqrtf(pd_rv[t0] + 1e-5f);
        bnc[128 + t0] = sp;
        bnc[192 + t0] = pd_be[t0] - pd_rm[t0] * sp;
    }
    for (int i = t0; i < 64*RS; i += 4096) {
        const int n = i / RS, k = i % RS;
        const float v = (k < 33) ? lin_w[k*64 + n] : 0.f;
        u16 h, l; splitbf(v, h, l);
        lint[i] = h; lint[64*RS + i] = l;
    }
    for (int b = 0; b < 3; b++) {
        const float* M = (b == 0) ? nn1_w : (b == 1) ? nd1_w : pd1_w;
        u16* dst = w1t3 + (size_t)b * 2 * 64 * RS;
        for (int i = t0; i < 64*RS; i += 4096) {
            const int o = i / RS, k = i % RS;
            const float v = (k < 64) ? M[k*64 + o] : 0.f;
            u16 h, l; splitbf(v, h, l);
            dst[i] = h; dst[64*RS + i] = l;
        }
        u16* d2 = w2t3 + (size_t)b * 2 * 16 * RS;
        for (int i = t0; i < 16*RS; i += 4096) {
            const int n = i / RS, k = i % RS;
            float v = 0.f;
            if (k < 64) {
                if (b == 0)      { if (n == 14)           v = nn2_w[k]; }
                else if (b == 1) { if (n < 11)            v = nd2_w[k*11 + n]; }
                else             { if (n >= 11 && n < 14) v = pd2_w[k*3 + (n-11)]; }
            }
            u16 h, l; splitbf(v, h, l);
            d2[i] = h; d2[16*RS + i] = l;
        }
    }
}

// ---------------------------------------------------------------------------
// k_mfma: wave-independent (no barriers/atomics). 2 chunks x 16 graphs/wave,
// X-buffer reused as T. Phase A: K=32 via split-MFMA + EXACT f32 rank-1
// update for the tp column (j=32) -> no padding, fewer MFMAs, better logit
// precision. Split-bf16 for nn branch; decode branches single-bf16.
// Flags: exact rule (saturated exempt) packed one u32/wave via __ballot.
// C/D layout (m89): col=lane&15, row=(lane>>4)*4+reg.
// ---------------------------------------------------------------------------
__global__ __launch_bounds__(256)
void k_mfma(const float* __restrict__ z, const float* __restrict__ tpr,
            const float* __restrict__ lin_w, const float* __restrict__ lin_b,
            const u16* __restrict__ lint, const u16* __restrict__ w1t3,
            const u16* __restrict__ w2t3,
            const float* __restrict__ nn1_b, const float* __restrict__ nd1_b,
            const float* __restrict__ pd1_b,
            const float* __restrict__ nn2_b, const float* __restrict__ nd2_b,
            const float* __restrict__ pd2_b,
            const float* __restrict__ bnc,
            const float* __restrict__ nsc, const float* __restrict__ nsh,
            const float* __restrict__ psc, const float* __restrict__ psh,
            float* __restrict__ nf_g, float* __restrict__ pos_g,
            int* __restrict__ nn_int, float* __restrict__ out_nn,
            u32* __restrict__ fmask, int B)
{
    __shared__ __align__(16) u16 sXT[4][2*16*RS];  // X(cols<32), then T (hi|lo)
    __shared__ __align__(16) u16 sH[4][2*16*RS];   // H (hi|lo)

    const int t    = threadIdx.x;
    const int lane = t & 63;
    const int w    = t >> 6;
    u16* mX = sXT[w];
    u16* mH = sH[w];

    const int W = blockIdx.x * 4 + w;            // global wave id

    auto gfrag = [&](const u16* base, int row0, int ks) -> short8v {
        const uint4 v = *(const uint4*)(base + (row0 + (lane & 15))*RS + ks*32 + ((lane >> 4) * 8));
        return __builtin_bit_cast(short8v, v);
    };
    short8v fLin[4], fW[3][4][2], fH2[3][2];
    #pragma unroll
    for (int nt = 0; nt < 4; nt++)
        fLin[nt] = gfrag(lint, nt*16, 0);        // K=32: ks=0 only
    #pragma unroll
    for (int b = 0; b < 3; b++)
        #pragma unroll
        for (int nt = 0; nt < 4; nt++)
            #pragma unroll
            for (int ks = 0; ks < 2; ks++)
                fW[b][nt][ks] = gfrag(w1t3 + (size_t)b*2*64*RS, nt*16, ks);
    #pragma unroll
    for (int b = 0; b < 3; b++)
        #pragma unroll
        for (int ks = 0; ks < 2; ks++)
            fH2[b][ks] = gfrag(w2t3 + (size_t)b*2*16*RS, 0, ks);

    const int col = lane & 15;
    float bLin[4], lin32c[4], bB1[3][4], bSc[2][4], bBi[2][4];
    #pragma unroll
    for (int nt = 0; nt < 4; nt++) {
        const int c = nt*16 + col;
        bLin[nt]    = lin_b[c];
        lin32c[nt]  = lin_w[32*64 + c];          // exact f32 tp column
        bB1[0][nt]  = nn1_b[c];
        bB1[1][nt]  = nd1_b[c];
        bB1[2][nt]  = pd1_b[c];
        bSc[0][nt]  = bnc[c];        bBi[0][nt] = bnc[64 + c];
        bSc[1][nt]  = bnc[128 + c];  bBi[1][nt] = bnc[192 + c];
    }
    const float epb = (col < 11) ? nd2_b[col] : (col < 14) ? pd2_b[col - 11] : 0.f;
    const float nn2b = nn2_b[0];
    const float a_ns = nsc[0], a_nh = nsh[0], a_ps = psc[0], a_ph = psh[0];

    auto ldfrag = [&](const u16* base, int ks) -> short8v {
        const uint4 v = *(const uint4*)(base + (lane & 15)*RS + ks*32 + ((lane >> 4) * 8));
        return __builtin_bit_cast(short8v, v);
    };

    u32 wavebits = 0;

    #pragma unroll 1
    for (int c = 0; c < 2; c++) {
        const int gb = (W*2 + c) * 16;
        if (gb >= B) break;

        // ---- stage X cols 0..31 (hi|lo) ----
        {
            const float4* zb = (const float4*)(z + (size_t)gb * 32);
            const float4 v0 = zb[(lane >> 2)*8 + (lane & 3)*2];
            const float4 v1 = zb[(lane >> 2)*8 + (lane & 3)*2 + 1];
            const float xv[8] = {v0.x, v0.y, v0.z, v0.w, v1.x, v1.y, v1.z, v1.w};
            u32 pkh[4], pkl[4];
            #pragma unroll
            for (int q = 0; q < 4; q++) {
                u16 h0, l0, h1, l1;
                splitbf(xv[2*q], h0, l0);
                splitbf(xv[2*q+1], h1, l1);
                pkh[q] = (u32)h0 | ((u32)h1 << 16);
                pkl[q] = (u32)l0 | ((u32)l1 << 16);
            }
            *(uint4*)(mX + (lane >> 2)*RS + (lane & 3)*8) = *(uint4*)pkh;
            *(uint4*)(mX + 16*RS + (lane >> 2)*RS + (lane & 3)*8) = *(uint4*)pkl;
        }

        // per-thread tp values for the exact rank-1 update (rows r=0..3)
        const float4 tq = *(const float4*)(tpr + gb + (lane >> 4)*4);
        const float tpf[4] = {tq.x, tq.y, tq.z, tq.w};

        // ---- phase A (K=32 split, 3 MFMA/nt + f32 tp term): H = X@lin + b ----
        const short8v a0h = ldfrag(mX, 0);
        const short8v a0l = ldfrag(mX + 16*RS, 0);
        #pragma unroll
        for (int nt = 0; nt < 4; nt++) {
            const short8v bl0 = gfrag(lint + 64*RS, nt*16, 0);
            f32x4 acc = {0.f, 0.f, 0.f, 0.f};
            acc = __builtin_amdgcn_mfma_f32_16x16x32_bf16(a0h, fLin[nt], acc, 0, 0, 0);
            acc = __builtin_amdgcn_mfma_f32_16x16x32_bf16(a0h, bl0, acc, 0, 0, 0);
            acc = __builtin_amdgcn_mfma_f32_16x16x32_bf16(a0l, fLin[nt], acc, 0, 0, 0);
            const float bias = bLin[nt];
            const float l32 = lin32c[nt];
            #pragma unroll
            for (int r = 0; r < 4; r++) {
                const int row = (lane >> 4)*4 + r;
                const float hv = fmaf(tpf[r], l32, acc[r] + bias);
                u16 hh, hl; splitbf(hv, hh, hl);
                mH[row*RS + nt*16 + col] = hh;
                mH[16*RS + row*RS + nt*16 + col] = hl;
            }
        }

        u16* mT = mX;   // X dead; reuse as T (T uses all 64 cols, written below)
        const short8v h0h = ldfrag(mH, 0);
        const short8v h1h = ldfrag(mH, 1);
        f32x4 acc2 = {0.f, 0.f, 0.f, 0.f};

        // ---- nn branch (b=0, split) ----
        {
            const short8v h0l = ldfrag(mH + 16*RS, 0);
            const short8v h1l = ldfrag(mH + 16*RS, 1);
            const u16* wlo = w1t3 + 64*RS;   // b=0 lo plane
            #pragma unroll
            for (int nt = 0; nt < 4; nt++) {
                const short8v wl0 = gfrag(wlo, nt*16, 0);
                const short8v wl1 = gfrag(wlo, nt*16, 1);
                f32x4 acc = {0.f, 0.f, 0.f, 0.f};
                acc = __builtin_amdgcn_mfma_f32_16x16x32_bf16(h0h, fW[0][nt][0], acc, 0, 0, 0);
                acc = __builtin_amdgcn_mfma_f32_16x16x32_bf16(h1h, fW[0][nt][1], acc, 0, 0, 0);
                acc = __builtin_amdgcn_mfma_f32_16x16x32_bf16(h0h, wl0, acc, 0, 0, 0);
                acc = __builtin_amdgcn_mfma_f32_16x16x32_bf16(h1h, wl1, acc, 0, 0, 0);
                acc = __builtin_amdgcn_mfma_f32_16x16x32_bf16(h0l, fW[0][nt][0], acc, 0, 0, 0);
                acc = __builtin_amdgcn_mfma_f32_16x16x32_bf16(h1l, fW[0][nt][1], acc, 0, 0, 0);
                const float bb = bB1[0][nt];
                #pragma unroll
                for (int r = 0; r < 4; r++) {
                    const int row = (lane >> 4)*4 + r;
                    float rv = acc[r] + bb;
                    rv = rv > 0.f ? rv : 0.f;
                    u16 th, tl; splitbf(rv, th, tl);
                    mT[row*RS + nt*16 + col] = th;
                    mT[16*RS + row*RS + nt*16 + col] = tl;
                }
            }
            const short8v t0h = ldfrag(mT, 0);
            const short8v t1h = ldfrag(mT, 1);
            const short8v t0l = ldfrag(mT + 16*RS, 0);
            const short8v t1l = ldfrag(mT + 16*RS, 1);
            const short8v g2l0 = gfrag(w2t3 + 16*RS, 0, 0);
            const short8v g2l1 = gfrag(w2t3 + 16*RS, 0, 1);
            acc2 = __builtin_amdgcn_mfma_f32_16x16x32_bf16(t0h, fH2[0][0], acc2, 0, 0, 0);
            acc2 = __builtin_amdgcn_mfma_f32_16x16x32_bf16(t1h, fH2[0][1], acc2, 0, 0, 0);
            acc2 = __builtin_amdgcn_mfma_f32_16x16x32_bf16(t0h, g2l0, acc2, 0, 0, 0);
            acc2 = __builtin_amdgcn_mfma_f32_16x16x32_bf16(t1h, g2l1, acc2, 0, 0, 0);
            acc2 = __builtin_amdgcn_mfma_f32_16x16x32_bf16(t0l, fH2[0][0], acc2, 0, 0, 0);
            acc2 = __builtin_amdgcn_mfma_f32_16x16x32_bf16(t1l, fH2[0][1], acc2, 0, 0, 0);
        }

        // ---- decode branches (b=1,2, single-bf16) ----
        #pragma unroll
        for (int b = 1; b < 3; b++) {
            #pragma unroll
            for (int nt = 0; nt < 4; nt++) {
                f32x4 acc = {0.f, 0.f, 0.f, 0.f};
                acc = __builtin_amdgcn_mfma_f32_16x16x32_bf16(h0h, fW[b][nt][0], acc, 0, 0, 0);
                acc = __builtin_amdgcn_mfma_f32_16x16x32_bf16(h1h, fW[b][nt][1], acc, 0, 0, 0);
                const float bb = bB1[b][nt];
                const float sc = bSc[b-1][nt];
                const float bi = bBi[b-1][nt];
                #pragma unroll
                for (int r = 0; r < 4; r++) {
                    const int row = (lane >> 4)*4 + r;
                    float rv = acc[r] + bb;
                    rv = rv > 0.f ? rv : 0.f;
                    mT[row*RS + nt*16 + col] = f2bf(fmaf(rv, sc, bi));
                }
            }
            const short8v t0 = ldfrag(mT, 0);
            const short8v t1 = ldfrag(mT, 1);
            acc2 = __builtin_amdgcn_mfma_f32_16x16x32_bf16(t0, fH2[b][0], acc2, 0, 0, 0);
            acc2 = __builtin_amdgcn_mfma_f32_16x16x32_bf16(t1, fH2[b][1], acc2, 0, 0, 0);
        }

        // ---- epilogue: cols 0-10 nf, 11-13 pos, 14 logit ----
        u32 chunkbits = 0;
        #pragma unroll
        for (int r = 0; r < 4; r++) {
            const int g = gb + (lane >> 4)*4 + r;
            const float v = acc2[r];
            bool fl = false;
            if (col < 11) {
                nf_g[(size_t)g*NDF + col] = fmaf(v + epb, a_ns, a_nh);
            } else if (col < 14) {
                pos_g[(size_t)g*3 + (col - 11)] = fmaf(v + epb, a_ps, a_ph);
            } else if (col == 14) {
                const float logit = v + nn2b;
                const float arg = fmaf(1.f / (1.f + expf(-logit)), 30.f, 5.f);
                int n;
                if (arg < 5.03f) {
                    n = 5;                       // arg > 5 in BOTH precisions
                } else if (arg >= 34.97f) {
                    if (logit >= 38.f)      n = 35;
                    else { n = 34; fl = (logit > 37.f); }   // narrow band -> f64
                } else {
                    n = (int)arg;
                    fl = fabsf(arg - rintf(arg)) < 0.03f;
                }
                nn_int[g] = n;
                out_nn[g] = (float)n;
            }
            const u64 m = __ballot(fl);
            chunkbits |= (u32)(((m >> 14) & 1ull) << r)
                       | (u32)(((m >> 30) & 1ull) << (4 + r))
                       | (u32)(((m >> 46) & 1ull) << (8 + r))
                       | (u32)(((m >> 62) & 1ull) << (12 + r));
        }
        wavebits |= chunkbits << (16 * c);
    }

    if (lane == 0) fmask[W] = wavebits;
    (void)B;
}

// ---------------------------------------------------------------------------
// k_fixscan: per-block (256 graphs): (1) each wave re-derives its own flagged
// graphs in exact f64 (wave-local mask = 2 fmask words), updating nn_int /
// out_nn / an LDS copy; (2) block-inclusive prefix scan of the corrected
// counts -> part, bsum. Replaces the separate k_fix + k_scan1 launches.
// ---------------------------------------------------------------------------
__global__ __launch_bounds__(256)
void k_fixscan(const float* __restrict__ z, const float* __restrict__ tpr,
               const float* __restrict__ lin_w, const float* __restrict__ lin_b,
               const float* __restrict__ nn1_w, const float* __restrict__ nn1_b,
               const float* __restrict__ nn2_w, const float* __restrict__ nn2_b,
               const u32* __restrict__ fmask, int* __restrict__ nn_int,
               float* __restrict__ out_nn,
               int* __restrict__ part, int* __restrict__ bsum)
{
    __shared__ __align__(16) double hb[4][64];
    __shared__ int s_n[256];
    __shared__ int ws[4];

    const int t = threadIdx.x;
    const int lane = t & 63;
    const int w = t >> 6;
    const int g0 = blockIdx.x * 256;

    s_n[t] = nn_int[g0 + t];

    // ---- fix: wave w owns graphs g0 + w*64 .. +63 (fmask slots 2w, 2w+1) ----
    {
        const u32 m0 = fmask[blockIdx.x*8 + w*2];
        const u32 m1 = fmask[blockIdx.x*8 + w*2 + 1];
        u64 mask = (u64)m0 | ((u64)m1 << 32);
        const double b2 = (double)nn2_b[0];

        while (mask) {
            const int bpos = __ffsll(mask) - 1;
            mask &= mask - 1;
            const int g = g0 + w*64 + bpos;

            double h0 = (double)lin_b[lane], h1 = 0.0, h2 = 0.0, h3 = 0.0;
            for (int j = 0; j < 32; j += 4) {
                h0 = fma((double)z[(size_t)g*32 + j],     (double)lin_w[j*64 + lane],     h0);
                h1 = fma((double)z[(size_t)g*32 + j + 1], (double)lin_w[(j+1)*64 + lane], h1);
                h2 = fma((double)z[(size_t)g*32 + j + 2], (double)lin_w[(j+2)*64 + lane], h2);
                h3 = fma((double)z[(size_t)g*32 + j + 3], (double)lin_w[(j+3)*64 + lane], h3);
            }
            h0 = fma((double)tpr[g], (double)lin_w[32*64 + lane], h0);
            hb[w][lane] = (h0 + h1) + (h2 + h3);

            const double2* hp = (const double2*)hb[w];
            double a0 = (double)nn1_b[lane], a1 = 0.0, a2 = 0.0, a3 = 0.0;
            for (int m = 0; m < 16; m++) {
                const double2 p = hp[2*m];
                const double2 q = hp[2*m + 1];
                a0 = fma(p.x, (double)nn1_w[(4*m+0)*64 + lane], a0);
                a1 = fma(p.y, (double)nn1_w[(4*m+1)*64 + lane], a1);
                a2 = fma(q.x, (double)nn1_w[(4*m+2)*64 + lane], a2);
                a3 = fma(q.y, (double)nn1_w[(4*m+3)*64 + lane], a3);
            }
            const double a = (a0 + a1) + (a2 + a3);
            double v = (a > 0.0) ? a * (double)nn2_w[lane] : 0.0;
            for (int d = 32; d > 0; d >>= 1) v += __shfl_xor(v, d);
            const double logit = v + b2;

            if (lane == 0) {
                const double sg = 1.0 / (1.0 + exp(-logit));
                const int n = (int)(sg * 30.0 + 5.0);
                s_n[w*64 + bpos] = n;
                nn_int[g] = n;
                out_nn[g] = (float)n;
            }
        }
    }
    __syncthreads();

    // ---- scan of corrected counts ----
    int v = s_n[t];
    #pragma unroll
    for (int d = 1; d < 64; d <<= 1) {
        const int u = __shfl_up(v, d);
        if (lane >= d) v += u;
    }
    if (lane == 63) ws[w] = v;
    __syncthreads();
    int add = 0;
    #pragma unroll
    for (int q = 0; q < 3; q++) if (q < w) add += ws[q];
    v += add;
    part[g0 + t] = v;
    if (t == 255) bsum[blockIdx.x] = v;
}

// ---------------------------------------------------------------------------
// k_expand: integrates the block-sum scan (each block scans bsum[512] into
// LDS s_boff), then 2 rows/thread two-level binary search, LDS repack,
// coalesced float4 stores. Rows >= total repeat graph B-1 (JAX padding).
// ---------------------------------------------------------------------------
__global__ __launch_bounds__(256)
void k_expand(const int* __restrict__ part, const int* __restrict__ bsum,
              const float* __restrict__ nf_g, const float* __restrict__ pos_g,
              float* __restrict__ out, int B, int T, int nb)
{
    __shared__ __align__(16) float s_nf[512*NDF];
    __shared__ __align__(16) float s_ps[512*3];
    __shared__ int s_boff[513];
    __shared__ int ws2[4];
    const int t = threadIdx.x;
    const int lane = t & 63;
    const int wid = t >> 6;

    // ---- in-block exclusive scan of bsum[0..511] -> s_boff ----
    {
        const int v0 = bsum[2*t];
        const int v1 = bsum[2*t + 1];
        const int s = v0 + v1;
        int sc = s;
        #pragma unroll
        for (int d = 1; d < 64; d <<= 1) {
            const int u = __shfl_up(sc, d);
            if (lane >= d) sc += u;
        }
        if (lane == 63) ws2[wid] = sc;
        __syncthreads();
        int add = 0;
        #pragma unroll
        for (int q = 0; q < 3; q++) if (q < wid) add += ws2[q];
        sc += add;
        const int exc = sc - s;
        s_boff[2*t]     = exc;
        s_boff[2*t + 1] = exc + v0;
        if (t == 255) s_boff[512] = sc;   // grand total
    }
    __syncthreads();

    const int r0 = blockIdx.x * 512 + 2*t;

    int blo = 0, bhi = nb - 1;
    while (blo < bhi) {
        const int m = (blo + bhi + 1) >> 1;
        if (s_boff[m] <= r0) blo = m; else bhi = m - 1;
    }
    const int bi = blo;
    const int lr = r0 - s_boff[bi];
    int lo = 0, hi2 = 256;
    while (lo < hi2) {
        const int m = (lo + hi2) >> 1;
        if (part[bi*256 + m] <= lr) lo = m + 1; else hi2 = m;
    }
    int i0 = bi*256 + lo;
    i0 = (i0 < B) ? i0 : B - 1;
    const int Ci0 = s_boff[i0 >> 8] + part[i0];
    const int i1 = ((r0 + 1) >= Ci0 && i0 < B - 1) ? i0 + 1 : i0;

    #pragma unroll
    for (int j = 0; j < NDF; j++) {
        s_nf[(2*t)*NDF + j]     = nf_g[(size_t)i0*NDF + j];
        s_nf[(2*t + 1)*NDF + j] = nf_g[(size_t)i1*NDF + j];
    }
    #pragma unroll
    for (int j = 0; j < 3; j++) {
        s_ps[(2*t)*3 + j]     = pos_g[(size_t)i0*3 + j];
        s_ps[(2*t + 1)*3 + j] = pos_g[(size_t)i1*3 + j];
    }
    __syncthreads();

    float4* onf = (float4*)(out + (size_t)blockIdx.x * 512 * NDF);
    const float4* snf = (const float4*)s_nf;
    #pragma unroll
    for (int q = 0; q < 6; q++) {
        const int idx = q*256 + t;
        if (idx < 512*NDF/4) onf[idx] = snf[idx];
    }
    float4* ops = (float4*)(out + (size_t)T*NDF + (size_t)blockIdx.x * 512 * 3);
    const float4* sps = (const float4*)s_ps;
    #pragma unroll
    for (int q = 0; q < 2; q++) {
        const int idx = q*256 + t;
        if (idx < 384) ops[idx] = sps[idx];
    }
}

// ---------------------------------------------------------------------------
extern "C" void kernel_launch(void* const* d_in, const int* in_sizes, int n_in,
                              void* d_out, int out_size, void* d_ws, size_t ws_size,
                              hipStream_t stream)
{
    const float* z     = (const float*)d_in[0];
    const float* tpr   = (const float*)d_in[1];
    const int    B     = in_sizes[1];
    const int    T     = B * MAXN;

    const float* lin_w = (const float*)d_in[3];
    const float* lin_b = (const float*)d_in[4];
    const float* nn1_w = (const float*)d_in[5];
    const float* nn1_b = (const float*)d_in[6];
    const float* nn2_w = (const float*)d_in[7];
    const float* nn2_b = (const float*)d_in[8];
    const float* nd1_w = (const float*)d_in[9];
    const float* nd1_b = (const float*)d_in[10];
    const float* nd_g  = (const float*)d_in[11];
    const float* nd_be = (const float*)d_in[12];
    const float* nd_rm = (const float*)d_in[13];
    const float* nd_rv = (const float*)d_in[14];
    const float* nd2_w = (const float*)d_in[15];
    const float* nd2_b = (const float*)d_in[16];
    const float* pd1_w = (const float*)d_in[17];
    const float* pd1_b = (const float*)d_in[18];
    const float* pd_g  = (const float*)d_in[19];
    const float* pd_be = (const float*)d_in[20];
    const float* pd_rm = (const float*)d_in[21];
    const float* pd_rv = (const float*)d_in[22];
    const float* pd2_w = (const float*)d_in[23];
    const float* pd2_b = (const float*)d_in[24];
    const float* nsc   = (const float*)d_in[25];
    const float* nsh   = (const float*)d_in[26];
    const float* psc   = (const float*)d_in[27];
    const float* psh   = (const float*)d_in[28];

    float* out = (float*)d_out;

    char* wsp = (char*)d_ws;
    size_t off = 0;
    auto take = [&](size_t bytes) { void* p = wsp + off; off = (off + bytes + 255) & ~(size_t)255; return p; };

    u16*   lint  = (u16*)take(2*64*RS*sizeof(u16));
    u16*   w1t3  = (u16*)take(3*2*64*RS*sizeof(u16));
    u16*   w2t3  = (u16*)take(3*2*16*RS*sizeof(u16));
    float* bnc   = (float*)take(256*sizeof(float));
    u32*   fmask = (u32*)take((size_t)(B/32)*sizeof(u32));
    float* nf_g  = (float*)take((size_t)B*NDF*sizeof(float));
    float* pos_g = (float*)take((size_t)B*3*sizeof(float));
    int*   nn_i  = (int*)take((size_t)B*sizeof(int));
    int*   part  = (int*)take((size_t)B*sizeof(int));
    int*   bsum  = (int*)take(4096*sizeof(int));

    const int nb = B / 256;   // 512

    k_prep<<<16, 256, 0, stream>>>(lin_w, nn1_w, nn2_w, nd1_w, nd2_w, pd1_w, pd2_w,
                                   nd_g, nd_be, nd_rm, nd_rv,
                                   pd_g, pd_be, pd_rm, pd_rv,
                                   lint, w1t3, w2t3, bnc);

    k_mfma<<<B/128, 256, 0, stream>>>(z, tpr, lin_w, lin_b, lint, w1t3, w2t3,
                                      nn1_b, nd1_b, pd1_b, nn2_b, nd2_b, pd2_b,
                                      bnc, nsc, nsh, psc, psh,
                                      nf_g, pos_g, nn_i, out + (size_t)T*14,
                                      fmask, B);

    k_fixscan<<<nb, 256, 0, stream>>>(z, tpr, lin_w, lin_b, nn1_w, nn1_b,
                                      nn2_w, nn2_b, fmask, nn_i,
                                      out + (size_t)T*14, part, bsum);

    k_expand<<<T/512, 256, 0, stream>>>(part, bsum, nf_g, pos_g, out, B, T, nb);

    (void)n_in; (void)out_size; (void)ws_size;
}

// Round 16
// 134.997 us; speedup vs baseline: 1.1009x; 1.0084x over previous
//
#include <hip/hip_runtime.h>
#include <math.h>

typedef unsigned int u32;
typedef unsigned short u16;
typedef unsigned long long u64;
typedef __attribute__((ext_vector_type(8))) short short8v;   // 8 bf16 = 4 VGPR
typedef __attribute__((ext_vector_type(4))) float f32x4;

#define NDF 11
#define MAXN 35
#define RS 72          // padded row stride in bf16 elems (144 B; 16B-aligned rows)
#define NFP 12         // padded nf_g row (f32) -> 48 B, 16B-aligned
#define PSP 4          // padded pos_g row (f32) -> 16 B

__device__ __forceinline__ u16 f2bf(float x) {
    u32 b = __float_as_uint(x);
    u32 r = (b + 0x7fffu + ((b >> 16) & 1u)) >> 16;
    return (u16)r;
}
__device__ __forceinline__ float bf2f(u16 h) {
    return __uint_as_float(((u32)h) << 16);
}
__device__ __forceinline__ void splitbf(float x, u16& hi, u16& lo) {
    hi = f2bf(x);
    lo = f2bf(x - bf2f(hi));
}

// ---------------------------------------------------------------------------
// k_prep: split-bf16 (hi|lo planes) transposed weight images + BN constants.
// ---------------------------------------------------------------------------
__global__ void k_prep(const float* __restrict__ lin_w,
                       const float* __restrict__ nn1_w, const float* __restrict__ nn2_w,
                       const float* __restrict__ nd1_w, const float* __restrict__ nd2_w,
                       const float* __restrict__ pd1_w, const float* __restrict__ pd2_w,
                       const float* __restrict__ nd_g, const float* __restrict__ nd_be,
                       const float* __restrict__ nd_rm, const float* __restrict__ nd_rv,
                       const float* __restrict__ pd_g, const float* __restrict__ pd_be,
                       const float* __restrict__ pd_rm, const float* __restrict__ pd_rv,
                       u16* __restrict__ lint, u16* __restrict__ w1t3,
                       u16* __restrict__ w2t3, float* __restrict__ bnc)
{
    const int t0 = blockIdx.x * 256 + threadIdx.x;     // 16 blocks -> 4096
    if (t0 < 64) {
        const float sc = nd_g[t0] / sqrtf(nd_rv[t0] + 1e-5f);
        bnc[t0]       = sc;
        bnc[64 + t0]  = nd_be[t0] - nd_rm[t0] * sc;
        const float sp = pd_g[t0] / sqrtf(pd_rv[t0] + 1e-5f);
        bnc[128 + t0] = sp;
        bnc[192 + t0] = pd_be[t0] - pd_rm[t0] * sp;
    }
    for (int i = t0; i < 64*RS; i += 4096) {
        const int n = i / RS, k = i % RS;
        const float v = (k < 33) ? lin_w[k*64 + n] : 0.f;
        u16 h, l; splitbf(v, h, l);
        lint[i] = h; lint[64*RS + i] = l;
    }
    for (int b = 0; b < 3; b++) {
        const float* M = (b == 0) ? nn1_w : (b == 1) ? nd1_w : pd1_w;
        u16* dst = w1t3 + (size_t)b * 2 * 64 * RS;
        for (int i = t0; i < 64*RS; i += 4096) {
            const int o = i / RS, k = i % RS;
            const float v = (k < 64) ? M[k*64 + o] : 0.f;
            u16 h, l; splitbf(v, h, l);
            dst[i] = h; dst[64*RS + i] = l;
        }
        u16* d2 = w2t3 + (size_t)b * 2 * 16 * RS;
        for (int i = t0; i < 16*RS; i += 4096) {
            const int n = i / RS, k = i % RS;
            float v = 0.f;
            if (k < 64) {
                if (b == 0)      { if (n == 14)           v = nn2_w[k]; }
                else if (b == 1) { if (n < 11)            v = nd2_w[k*11 + n]; }
                else             { if (n >= 11 && n < 14) v = pd2_w[k*3 + (n-11)]; }
            }
            u16 h, l; splitbf(v, h, l);
            d2[i] = h; d2[16*RS + i] = l;
        }
    }
}

// ---------------------------------------------------------------------------
// k_mfma: wave-independent (no barriers/atomics). 2 chunks x 16 graphs/wave,
// X-buffer reused as T. Phase A: K=32 via split-MFMA + EXACT f32 rank-1
// update for the tp column. Split-bf16 for nn branch; decode single-bf16.
// Writes nf_g/pos_g at PADDED strides (NFP/PSP) for vectorized expand reads.
// Flags: exact rule (saturated exempt), one u32/wave via __ballot.
// C/D layout (m89): col=lane&15, row=(lane>>4)*4+reg.
// ---------------------------------------------------------------------------
__global__ __launch_bounds__(256)
void k_mfma(const float* __restrict__ z, const float* __restrict__ tpr,
            const float* __restrict__ lin_w, const float* __restrict__ lin_b,
            const u16* __restrict__ lint, const u16* __restrict__ w1t3,
            const u16* __restrict__ w2t3,
            const float* __restrict__ nn1_b, const float* __restrict__ nd1_b,
            const float* __restrict__ pd1_b,
            const float* __restrict__ nn2_b, const float* __restrict__ nd2_b,
            const float* __restrict__ pd2_b,
            const float* __restrict__ bnc,
            const float* __restrict__ nsc, const float* __restrict__ nsh,
            const float* __restrict__ psc, const float* __restrict__ psh,
            float* __restrict__ nf_g, float* __restrict__ pos_g,
            int* __restrict__ nn_int, float* __restrict__ out_nn,
            u32* __restrict__ fmask, int B)
{
    __shared__ __align__(16) u16 sXT[4][2*16*RS];  // X(cols<32), then T (hi|lo)
    __shared__ __align__(16) u16 sH[4][2*16*RS];   // H (hi|lo)

    const int t    = threadIdx.x;
    const int lane = t & 63;
    const int w    = t >> 6;
    u16* mX = sXT[w];
    u16* mH = sH[w];

    const int W = blockIdx.x * 4 + w;            // global wave id

    auto gfrag = [&](const u16* base, int row0, int ks) -> short8v {
        const uint4 v = *(const uint4*)(base + (row0 + (lane & 15))*RS + ks*32 + ((lane >> 4) * 8));
        return __builtin_bit_cast(short8v, v);
    };
    short8v fLin[4], fW[3][4][2], fH2[3][2];
    #pragma unroll
    for (int nt = 0; nt < 4; nt++)
        fLin[nt] = gfrag(lint, nt*16, 0);        // K=32: ks=0 only
    #pragma unroll
    for (int b = 0; b < 3; b++)
        #pragma unroll
        for (int nt = 0; nt < 4; nt++)
            #pragma unroll
            for (int ks = 0; ks < 2; ks++)
                fW[b][nt][ks] = gfrag(w1t3 + (size_t)b*2*64*RS, nt*16, ks);
    #pragma unroll
    for (int b = 0; b < 3; b++)
        #pragma unroll
        for (int ks = 0; ks < 2; ks++)
            fH2[b][ks] = gfrag(w2t3 + (size_t)b*2*16*RS, 0, ks);

    const int col = lane & 15;
    float bLin[4], lin32c[4], bB1[3][4], bSc[2][4], bBi[2][4];
    #pragma unroll
    for (int nt = 0; nt < 4; nt++) {
        const int c = nt*16 + col;
        bLin[nt]    = lin_b[c];
        lin32c[nt]  = lin_w[32*64 + c];          // exact f32 tp column
        bB1[0][nt]  = nn1_b[c];
        bB1[1][nt]  = nd1_b[c];
        bB1[2][nt]  = pd1_b[c];
        bSc[0][nt]  = bnc[c];        bBi[0][nt] = bnc[64 + c];
        bSc[1][nt]  = bnc[128 + c];  bBi[1][nt] = bnc[192 + c];
    }
    const float epb = (col < 11) ? nd2_b[col] : (col < 14) ? pd2_b[col - 11] : 0.f;
    const float nn2b = nn2_b[0];
    const float a_ns = nsc[0], a_nh = nsh[0], a_ps = psc[0], a_ph = psh[0];

    auto ldfrag = [&](const u16* base, int ks) -> short8v {
        const uint4 v = *(const uint4*)(base + (lane & 15)*RS + ks*32 + ((lane >> 4) * 8));
        return __builtin_bit_cast(short8v, v);
    };

    u32 wavebits = 0;

    #pragma unroll 1
    for (int c = 0; c < 2; c++) {
        const int gb = (W*2 + c) * 16;
        if (gb >= B) break;

        // ---- stage X cols 0..31 (hi|lo) ----
        {
            const float4* zb = (const float4*)(z + (size_t)gb * 32);
            const float4 v0 = zb[(lane >> 2)*8 + (lane & 3)*2];
            const float4 v1 = zb[(lane >> 2)*8 + (lane & 3)*2 + 1];
            const float xv[8] = {v0.x, v0.y, v0.z, v0.w, v1.x, v1.y, v1.z, v1.w};
            u32 pkh[4], pkl[4];
            #pragma unroll
            for (int q = 0; q < 4; q++) {
                u16 h0, l0, h1, l1;
                splitbf(xv[2*q], h0, l0);
                splitbf(xv[2*q+1], h1, l1);
                pkh[q] = (u32)h0 | ((u32)h1 << 16);
                pkl[q] = (u32)l0 | ((u32)l1 << 16);
            }
            *(uint4*)(mX + (lane >> 2)*RS + (lane & 3)*8) = *(uint4*)pkh;
            *(uint4*)(mX + 16*RS + (lane >> 2)*RS + (lane & 3)*8) = *(uint4*)pkl;
        }

        // per-thread tp values for the exact rank-1 update (rows r=0..3)
        const float4 tq = *(const float4*)(tpr + gb + (lane >> 4)*4);
        const float tpf[4] = {tq.x, tq.y, tq.z, tq.w};

        // ---- phase A (K=32 split, 3 MFMA/nt + f32 tp term): H = X@lin + b ----
        const short8v a0h = ldfrag(mX, 0);
        const short8v a0l = ldfrag(mX + 16*RS, 0);
        #pragma unroll
        for (int nt = 0; nt < 4; nt++) {
            const short8v bl0 = gfrag(lint + 64*RS, nt*16, 0);
            f32x4 acc = {0.f, 0.f, 0.f, 0.f};
            acc = __builtin_amdgcn_mfma_f32_16x16x32_bf16(a0h, fLin[nt], acc, 0, 0, 0);
            acc = __builtin_amdgcn_mfma_f32_16x16x32_bf16(a0h, bl0, acc, 0, 0, 0);
            acc = __builtin_amdgcn_mfma_f32_16x16x32_bf16(a0l, fLin[nt], acc, 0, 0, 0);
            const float bias = bLin[nt];
            const float l32 = lin32c[nt];
            #pragma unroll
            for (int r = 0; r < 4; r++) {
                const int row = (lane >> 4)*4 + r;
                const float hv = fmaf(tpf[r], l32, acc[r] + bias);
                u16 hh, hl; splitbf(hv, hh, hl);
                mH[row*RS + nt*16 + col] = hh;
                mH[16*RS + row*RS + nt*16 + col] = hl;
            }
        }

        u16* mT = mX;   // X dead; reuse as T
        const short8v h0h = ldfrag(mH, 0);
        const short8v h1h = ldfrag(mH, 1);
        f32x4 acc2 = {0.f, 0.f, 0.f, 0.f};

        // ---- nn branch (b=0, split) ----
        {
            const short8v h0l = ldfrag(mH + 16*RS, 0);
            const short8v h1l = ldfrag(mH + 16*RS, 1);
            const u16* wlo = w1t3 + 64*RS;   // b=0 lo plane
            #pragma unroll
            for (int nt = 0; nt < 4; nt++) {
                const short8v wl0 = gfrag(wlo, nt*16, 0);
                const short8v wl1 = gfrag(wlo, nt*16, 1);
                f32x4 acc = {0.f, 0.f, 0.f, 0.f};
                acc = __builtin_amdgcn_mfma_f32_16x16x32_bf16(h0h, fW[0][nt][0], acc, 0, 0, 0);
                acc = __builtin_amdgcn_mfma_f32_16x16x32_bf16(h1h, fW[0][nt][1], acc, 0, 0, 0);
                acc = __builtin_amdgcn_mfma_f32_16x16x32_bf16(h0h, wl0, acc, 0, 0, 0);
                acc = __builtin_amdgcn_mfma_f32_16x16x32_bf16(h1h, wl1, acc, 0, 0, 0);
                acc = __builtin_amdgcn_mfma_f32_16x16x32_bf16(h0l, fW[0][nt][0], acc, 0, 0, 0);
                acc = __builtin_amdgcn_mfma_f32_16x16x32_bf16(h1l, fW[0][nt][1], acc, 0, 0, 0);
                const float bb = bB1[0][nt];
                #pragma unroll
                for (int r = 0; r < 4; r++) {
                    const int row = (lane >> 4)*4 + r;
                    float rv = acc[r] + bb;
                    rv = rv > 0.f ? rv : 0.f;
                    u16 th, tl; splitbf(rv, th, tl);
                    mT[row*RS + nt*16 + col] = th;
                    mT[16*RS + row*RS + nt*16 + col] = tl;
                }
            }
            const short8v t0h = ldfrag(mT, 0);
            const short8v t1h = ldfrag(mT, 1);
            const short8v t0l = ldfrag(mT + 16*RS, 0);
            const short8v t1l = ldfrag(mT + 16*RS, 1);
            const short8v g2l0 = gfrag(w2t3 + 16*RS, 0, 0);
            const short8v g2l1 = gfrag(w2t3 + 16*RS, 0, 1);
            acc2 = __builtin_amdgcn_mfma_f32_16x16x32_bf16(t0h, fH2[0][0], acc2, 0, 0, 0);
            acc2 = __builtin_amdgcn_mfma_f32_16x16x32_bf16(t1h, fH2[0][1], acc2, 0, 0, 0);
            acc2 = __builtin_amdgcn_mfma_f32_16x16x32_bf16(t0h, g2l0, acc2, 0, 0, 0);
            acc2 = __builtin_amdgcn_mfma_f32_16x16x32_bf16(t1h, g2l1, acc2, 0, 0, 0);
            acc2 = __builtin_amdgcn_mfma_f32_16x16x32_bf16(t0l, fH2[0][0], acc2, 0, 0, 0);
            acc2 = __builtin_amdgcn_mfma_f32_16x16x32_bf16(t1l, fH2[0][1], acc2, 0, 0, 0);
        }

        // ---- decode branches (b=1,2, single-bf16) ----
        #pragma unroll
        for (int b = 1; b < 3; b++) {
            #pragma unroll
            for (int nt = 0; nt < 4; nt++) {
                f32x4 acc = {0.f, 0.f, 0.f, 0.f};
                acc = __builtin_amdgcn_mfma_f32_16x16x32_bf16(h0h, fW[b][nt][0], acc, 0, 0, 0);
                acc = __builtin_amdgcn_mfma_f32_16x16x32_bf16(h1h, fW[b][nt][1], acc, 0, 0, 0);
                const float bb = bB1[b][nt];
                const float sc = bSc[b-1][nt];
                const float bi = bBi[b-1][nt];
                #pragma unroll
                for (int r = 0; r < 4; r++) {
                    const int row = (lane >> 4)*4 + r;
                    float rv = acc[r] + bb;
                    rv = rv > 0.f ? rv : 0.f;
                    mT[row*RS + nt*16 + col] = f2bf(fmaf(rv, sc, bi));
                }
            }
            const short8v t0 = ldfrag(mT, 0);
            const short8v t1 = ldfrag(mT, 1);
            acc2 = __builtin_amdgcn_mfma_f32_16x16x32_bf16(t0, fH2[b][0], acc2, 0, 0, 0);
            acc2 = __builtin_amdgcn_mfma_f32_16x16x32_bf16(t1, fH2[b][1], acc2, 0, 0, 0);
        }

        // ---- epilogue: cols 0-10 nf, 11-13 pos, 14 logit (padded strides) ----
        u32 chunkbits = 0;
        #pragma unroll
        for (int r = 0; r < 4; r++) {
            const int g = gb + (lane >> 4)*4 + r;
            const float v = acc2[r];
            bool fl = false;
            if (col < 11) {
                nf_g[(size_t)g*NFP + col] = fmaf(v + epb, a_ns, a_nh);
            } else if (col < 14) {
                pos_g[(size_t)g*PSP + (col - 11)] = fmaf(v + epb, a_ps, a_ph);
            } else if (col == 14) {
                const float logit = v + nn2b;
                const float arg = fmaf(1.f / (1.f + expf(-logit)), 30.f, 5.f);
                int n;
                if (arg < 5.03f) {
                    n = 5;                       // arg > 5 in BOTH precisions
                } else if (arg >= 34.97f) {
                    if (logit >= 38.f)      n = 35;
                    else { n = 34; fl = (logit > 37.f); }   // narrow band -> f64
                } else {
                    n = (int)arg;
                    fl = fabsf(arg - rintf(arg)) < 0.03f;
                }
                nn_int[g] = n;
                out_nn[g] = (float)n;
            }
            const u64 m = __ballot(fl);
            chunkbits |= (u32)(((m >> 14) & 1ull) << r)
                       | (u32)(((m >> 30) & 1ull) << (4 + r))
                       | (u32)(((m >> 46) & 1ull) << (8 + r))
                       | (u32)(((m >> 62) & 1ull) << (12 + r));
        }
        wavebits |= chunkbits << (16 * c);
    }

    if (lane == 0) fmask[W] = wavebits;
    (void)B;
}

// ---------------------------------------------------------------------------
// k_fixscan: per-block (256 graphs): fix flagged graphs in exact f64, then
// block-inclusive prefix scan of corrected counts -> part, bsum.
// ---------------------------------------------------------------------------
__global__ __launch_bounds__(256)
void k_fixscan(const float* __restrict__ z, const float* __restrict__ tpr,
               const float* __restrict__ lin_w, const float* __restrict__ lin_b,
               const float* __restrict__ nn1_w, const float* __restrict__ nn1_b,
               const float* __restrict__ nn2_w, const float* __restrict__ nn2_b,
               const u32* __restrict__ fmask, int* __restrict__ nn_int,
               float* __restrict__ out_nn,
               int* __restrict__ part, int* __restrict__ bsum)
{
    __shared__ __align__(16) double hb[4][64];
    __shared__ int s_n[256];
    __shared__ int ws[4];

    const int t = threadIdx.x;
    const int lane = t & 63;
    const int w = t >> 6;
    const int g0 = blockIdx.x * 256;

    s_n[t] = nn_int[g0 + t];

    {
        const u32 m0 = fmask[blockIdx.x*8 + w*2];
        const u32 m1 = fmask[blockIdx.x*8 + w*2 + 1];
        u64 mask = (u64)m0 | ((u64)m1 << 32);
        const double b2 = (double)nn2_b[0];

        while (mask) {
            const int bpos = __ffsll(mask) - 1;
            mask &= mask - 1;
            const int g = g0 + w*64 + bpos;

            double h0 = (double)lin_b[lane], h1 = 0.0, h2 = 0.0, h3 = 0.0;
            for (int j = 0; j < 32; j += 4) {
                h0 = fma((double)z[(size_t)g*32 + j],     (double)lin_w[j*64 + lane],     h0);
                h1 = fma((double)z[(size_t)g*32 + j + 1], (double)lin_w[(j+1)*64 + lane], h1);
                h2 = fma((double)z[(size_t)g*32 + j + 2], (double)lin_w[(j+2)*64 + lane], h2);
                h3 = fma((double)z[(size_t)g*32 + j + 3], (double)lin_w[(j+3)*64 + lane], h3);
            }
            h0 = fma((double)tpr[g], (double)lin_w[32*64 + lane], h0);
            hb[w][lane] = (h0 + h1) + (h2 + h3);

            const double2* hp = (const double2*)hb[w];
            double a0 = (double)nn1_b[lane], a1 = 0.0, a2 = 0.0, a3 = 0.0;
            for (int m = 0; m < 16; m++) {
                const double2 p = hp[2*m];
                const double2 q = hp[2*m + 1];
                a0 = fma(p.x, (double)nn1_w[(4*m+0)*64 + lane], a0);
                a1 = fma(p.y, (double)nn1_w[(4*m+1)*64 + lane], a1);
                a2 = fma(q.x, (double)nn1_w[(4*m+2)*64 + lane], a2);
                a3 = fma(q.y, (double)nn1_w[(4*m+3)*64 + lane], a3);
            }
            const double a = (a0 + a1) + (a2 + a3);
            double v = (a > 0.0) ? a * (double)nn2_w[lane] : 0.0;
            for (int d = 32; d > 0; d >>= 1) v += __shfl_xor(v, d);
            const double logit = v + b2;

            if (lane == 0) {
                const double sg = 1.0 / (1.0 + exp(-logit));
                const int n = (int)(sg * 30.0 + 5.0);
                s_n[w*64 + bpos] = n;
                nn_int[g] = n;
                out_nn[g] = (float)n;
            }
        }
    }
    __syncthreads();

    int v = s_n[t];
    #pragma unroll
    for (int d = 1; d < 64; d <<= 1) {
        const int u = __shfl_up(v, d);
        if (lane >= d) v += u;
    }
    if (lane == 63) ws[w] = v;
    __syncthreads();
    int add = 0;
    #pragma unroll
    for (int q = 0; q < 3; q++) if (q < w) add += ws[q];
    v += add;
    part[g0 + t] = v;
    if (t == 255) bsum[blockIdx.x] = v;
}

// ---------------------------------------------------------------------------
// k_expand: in-block scan of bsum -> s_boff; 2 rows/thread two-level binary
// search; VECTORIZED row gather (float4 from padded nf_g/pos_g); LDS repack;
// coalesced float4 stores. Rows >= total repeat graph B-1 (JAX padding).
// ---------------------------------------------------------------------------
__global__ __launch_bounds__(256)
void k_expand(const int* __restrict__ part, const int* __restrict__ bsum,
              const float* __restrict__ nf_g, const float* __restrict__ pos_g,
              float* __restrict__ out, int B, int T, int nb)
{
    __shared__ __align__(16) float s_nf[512*NDF];
    __shared__ __align__(16) float s_ps[512*3];
    __shared__ int s_boff[513];
    __shared__ int ws2[4];
    const int t = threadIdx.x;
    const int lane = t & 63;
    const int wid = t >> 6;

    // ---- in-block exclusive scan of bsum[0..511] -> s_boff ----
    {
        const int v0 = bsum[2*t];
        const int v1 = bsum[2*t + 1];
        const int s = v0 + v1;
        int sc = s;
        #pragma unroll
        for (int d = 1; d < 64; d <<= 1) {
            const int u = __shfl_up(sc, d);
            if (lane >= d) sc += u;
        }
        if (lane == 63) ws2[wid] = sc;
        __syncthreads();
        int add = 0;
        #pragma unroll
        for (int q = 0; q < 3; q++) if (q < wid) add += ws2[q];
        sc += add;
        const int exc = sc - s;
        s_boff[2*t]     = exc;
        s_boff[2*t + 1] = exc + v0;
        if (t == 255) s_boff[512] = sc;
    }
    __syncthreads();

    const int r0 = blockIdx.x * 512 + 2*t;

    int blo = 0, bhi = nb - 1;
    while (blo < bhi) {
        const int m = (blo + bhi + 1) >> 1;
        if (s_boff[m] <= r0) blo = m; else bhi = m - 1;
    }
    const int bi = blo;
    const int lr = r0 - s_boff[bi];
    int lo = 0, hi2 = 256;
    while (lo < hi2) {
        const int m = (lo + hi2) >> 1;
        if (part[bi*256 + m] <= lr) lo = m + 1; else hi2 = m;
    }
    int i0 = bi*256 + lo;
    i0 = (i0 < B) ? i0 : B - 1;
    const int Ci0 = s_boff[i0 >> 8] + part[i0];
    const int i1 = ((r0 + 1) >= Ci0 && i0 < B - 1) ? i0 + 1 : i0;

    // ---- vectorized gather: 3 float4 per nf row, 1 float4 per pos row ----
    {
        const float4* n0 = (const float4*)(nf_g + (size_t)i0*NFP);
        const float4* n1 = (const float4*)(nf_g + (size_t)i1*NFP);
        const float4 a0 = n0[0], a1 = n0[1], a2 = n0[2];
        const float4 b0 = n1[0], b1 = n1[1], b2 = n1[2];
        float* d0 = s_nf + (2*t)*NDF;
        d0[0] = a0.x; d0[1] = a0.y; d0[2] = a0.z; d0[3] = a0.w;
        d0[4] = a1.x; d0[5] = a1.y; d0[6] = a1.z; d0[7] = a1.w;
        d0[8] = a2.x; d0[9] = a2.y; d0[10] = a2.z;
        float* d1 = s_nf + (2*t + 1)*NDF;
        d1[0] = b0.x; d1[1] = b0.y; d1[2] = b0.z; d1[3] = b0.w;
        d1[4] = b1.x; d1[5] = b1.y; d1[6] = b1.z; d1[7] = b1.w;
        d1[8] = b2.x; d1[9] = b2.y; d1[10] = b2.z;

        const float4 p0 = *(const float4*)(pos_g + (size_t)i0*PSP);
        const float4 p1 = *(const float4*)(pos_g + (size_t)i1*PSP);
        s_ps[(2*t)*3 + 0] = p0.x; s_ps[(2*t)*3 + 1] = p0.y; s_ps[(2*t)*3 + 2] = p0.z;
        s_ps[(2*t + 1)*3 + 0] = p1.x; s_ps[(2*t + 1)*3 + 1] = p1.y; s_ps[(2*t + 1)*3 + 2] = p1.z;
    }
    __syncthreads();

    float4* onf = (float4*)(out + (size_t)blockIdx.x * 512 * NDF);
    const float4* snf = (const float4*)s_nf;
    #pragma unroll
    for (int q = 0; q < 6; q++) {
        const int idx = q*256 + t;
        if (idx < 512*NDF/4) onf[idx] = snf[idx];
    }
    float4* ops = (float4*)(out + (size_t)T*NDF + (size_t)blockIdx.x * 512 * 3);
    const float4* sps = (const float4*)s_ps;
    #pragma unroll
    for (int q = 0; q < 2; q++) {
        const int idx = q*256 + t;
        if (idx < 384) ops[idx] = sps[idx];
    }
}

// ---------------------------------------------------------------------------
extern "C" void kernel_launch(void* const* d_in, const int* in_sizes, int n_in,
                              void* d_out, int out_size, void* d_ws, size_t ws_size,
                              hipStream_t stream)
{
    const float* z     = (const float*)d_in[0];
    const float* tpr   = (const float*)d_in[1];
    const int    B     = in_sizes[1];
    const int    T     = B * MAXN;

    const float* lin_w = (const float*)d_in[3];
    const float* lin_b = (const float*)d_in[4];
    const float* nn1_w = (const float*)d_in[5];
    const float* nn1_b = (const float*)d_in[6];
    const float* nn2_w = (const float*)d_in[7];
    const float* nn2_b = (const float*)d_in[8];
    const float* nd1_w = (const float*)d_in[9];
    const float* nd1_b = (const float*)d_in[10];
    const float* nd_g  = (const float*)d_in[11];
    const float* nd_be = (const float*)d_in[12];
    const float* nd_rm = (const float*)d_in[13];
    const float* nd_rv = (const float*)d_in[14];
    const float* nd2_w = (const float*)d_in[15];
    const float* nd2_b = (const float*)d_in[16];
    const float* pd1_w = (const float*)d_in[17];
    const float* pd1_b = (const float*)d_in[18];
    const float* pd_g  = (const float*)d_in[19];
    const float* pd_be = (const float*)d_in[20];
    const float* pd_rm = (const float*)d_in[21];
    const float* pd_rv = (const float*)d_in[22];
    const float* pd2_w = (const float*)d_in[23];
    const float* pd2_b = (const float*)d_in[24];
    const float* nsc   = (const float*)d_in[25];
    const float* nsh   = (const float*)d_in[26];
    const float* psc   = (const float*)d_in[27];
    const float* psh   = (const float*)d_in[28];

    float* out = (float*)d_out;

    char* wsp = (char*)d_ws;
    size_t off = 0;
    auto take = [&](size_t bytes) { void* p = wsp + off; off = (off + bytes + 255) & ~(size_t)255; return p; };

    u16*   lint  = (u16*)take(2*64*RS*sizeof(u16));
    u16*   w1t3  = (u16*)take(3*2*64*RS*sizeof(u16));
    u16*   w2t3  = (u16*)take(3*2*16*RS*sizeof(u16));
    float* bnc   = (float*)take(256*sizeof(float));
    u32*   fmask = (u32*)take((size_t)(B/32)*sizeof(u32));
    float* nf_g  = (float*)take((size_t)B*NFP*sizeof(float));
    float* pos_g = (float*)take((size_t)B*PSP*sizeof(float));
    int*   nn_i  = (int*)take((size_t)B*sizeof(int));
    int*   part  = (int*)take((size_t)B*sizeof(int));
    int*   bsum  = (int*)take(4096*sizeof(int));

    const int nb = B / 256;   // 512

    k_prep<<<16, 256, 0, stream>>>(lin_w, nn1_w, nn2_w, nd1_w, nd2_w, pd1_w, pd2_w,
                                   nd_g, nd_be, nd_rm, nd_rv,
                                   pd_g, pd_be, pd_rm, pd_rv,
                                   lint, w1t3, w2t3, bnc);

    k_mfma<<<B/128, 256, 0, stream>>>(z, tpr, lin_w, lin_b, lint, w1t3, w2t3,
                                      nn1_b, nd1_b, pd1_b, nn2_b, nd2_b, pd2_b,
                                      bnc, nsc, nsh, psc, psh,
                                      nf_g, pos_g, nn_i, out + (size_t)T*14,
                                      fmask, B);

    k_fixscan<<<nb, 256, 0, stream>>>(z, tpr, lin_w, lin_b, nn1_w, nn1_b,
                                      nn2_w, nn2_b, fmask, nn_i,
                                      out + (size_t)T*14, part, bsum);

    k_expand<<<T/512, 256, 0, stream>>>(part, bsum, nf_g, pos_g, out, B, T, nb);

    (void)n_in; (void)out_size; (void)ws_size;
}